// Round 1
// baseline (2563.403 us; speedup 1.0000x reference)
//
#include <hip/hip_runtime.h>

typedef __bf16 bf16x8 __attribute__((ext_vector_type(8)));
typedef float f32x4 __attribute__((ext_vector_type(4)));

#define NTH  512
#define SEQT 256

// layer geometry
#define H_0 116
#define CAT_0 180
#define H_1 76
#define CAT_1 192
#define H_2 64
#define CAT_2 140
// LDS leading dims (bf16 elems); +8 pad breaks 32-way bank conflicts, keeps 16B align
#define LD_0 200
#define LD_1 200
#define LD_2 168
#define LD_M 72

struct KArgs { const float* in[30]; float* out; };

__device__ __forceinline__ float fast_tanh(float x) {
  return __fdividef(2.0f, 1.0f + __expf(-2.0f * x)) - 1.0f;
}
__device__ __forceinline__ float fast_sig(float x) {
  return __fdividef(1.0f, 1.0f + __expf(-x));
}

// sums layout: [(mat*128 + n)*17 + r], fp32
__device__ __forceinline__ float cfc_combine(const float* __restrict__ sums,
                                             const float* __restrict__ bias,
                                             int n, int r, int bstride) {
  float s1 = sums[(0*128 + n)*17 + r] + bias[0*bstride + n];
  float s2 = sums[(1*128 + n)*17 + r] + bias[1*bstride + n];
  float sa = sums[(2*128 + n)*17 + r] + bias[2*bstride + n];
  float sb = sums[(3*128 + n)*17 + r] + bias[3*bstride + n];
  float ff1 = fast_tanh(s1);
  float ff2 = fast_tanh(s2);
  float ti  = fast_sig(sa + sb);
  return ff1 + ti * (ff2 - ff1);
}

// One layer's matmul phase. Wave `w` owns units u = w + 8*i (u = Nt*4 + mat).
// D[n_loc][r] = sum_k W[n][k] * cat[r][k], accumulated over hi+lo activation parts.
template<int MAXU, int KT, int LD>
__device__ __forceinline__ void mfma_phase(const __bf16* __restrict__ ch,
                                           const __bf16* __restrict__ cl,
                                           const bf16x8 (*__restrict__ wf)[KT],
                                           float* __restrict__ sums,
                                           int w, int lane, int NU) {
  const int r  = lane & 15;
  const int kb = (lane >> 4) * 8;
  #pragma unroll
  for (int p = 0; p < (MAXU + 1) / 2; ++p) {
    const int i0 = 2 * p;
    const int i1 = 2 * p + 1;
    const bool v0 = (w + 8 * i0) < NU;
    const bool v1 = (i1 < MAXU) && ((w + 8 * i1) < NU);
    if (!(v0 || v1)) continue;
    f32x4 a0 = {0.f, 0.f, 0.f, 0.f};
    f32x4 a1 = {0.f, 0.f, 0.f, 0.f};
    #pragma unroll
    for (int kt = 0; kt < KT; ++kt) {
      const bf16x8 bh = *reinterpret_cast<const bf16x8*>(ch + r * LD + kt * 32 + kb);
      const bf16x8 bl = *reinterpret_cast<const bf16x8*>(cl + r * LD + kt * 32 + kb);
      if (v0) {
        a0 = __builtin_amdgcn_mfma_f32_16x16x32_bf16(wf[i0][kt], bh, a0, 0, 0, 0);
        a0 = __builtin_amdgcn_mfma_f32_16x16x32_bf16(wf[i0][kt], bl, a0, 0, 0, 0);
      }
      if (v1) {
        const int i1c = (i1 < MAXU) ? i1 : 0;  // keep static index in-bounds
        a1 = __builtin_amdgcn_mfma_f32_16x16x32_bf16(wf[i1c][kt], bh, a1, 0, 0, 0);
        a1 = __builtin_amdgcn_mfma_f32_16x16x32_bf16(wf[i1c][kt], bl, a1, 0, 0, 0);
      }
    }
    const int nq = (lane >> 4) * 4;
    if (v0) {
      const int u = w + 8 * i0, mat = u & 3, nb = (u >> 2) * 16 + nq;
      #pragma unroll
      for (int q = 0; q < 4; ++q) sums[(mat * 128 + nb + q) * 17 + r] = a0[q];
    }
    if (v1) {
      const int u = w + 8 * i1, mat = u & 3, nb = (u >> 2) * 16 + nq;
      #pragma unroll
      for (int q = 0; q < 4; ++q) sums[(mat * 128 + nb + q) * 17 + r] = a1[q];
    }
  }
}

__global__ __launch_bounds__(NTH, 2) void ncp_fused(KArgs args) {
  // cat buffers: bf16 hi/lo, [16 rows][LD], zero-padded K region
  __shared__ __align__(16) __bf16 s_c0h[16 * LD_0], s_c0l[16 * LD_0];
  __shared__ __align__(16) __bf16 s_c1h[16 * LD_1], s_c1l[16 * LD_1];
  __shared__ __align__(16) __bf16 s_c2h[16 * LD_2], s_c2l[16 * LD_2];
  __shared__ __align__(16) __bf16 s_mh[16 * LD_M], s_ml[16 * LD_M];
  __shared__ float s_sums[4 * 128 * 17];
  __shared__ float s_b0[4 * 128], s_b1[4 * 80], s_b2[4 * 64], s_bfc[64];

  const int tid  = threadIdx.x;
  const int w    = tid >> 6;
  const int lane = tid & 63;
  const int nl   = lane & 15;
  const int kb   = (lane >> 4) * 8;
  const int wgBase = blockIdx.x * 16;
  const float* __restrict__ xg = args.in[29];
  float* __restrict__ out = args.out;

  // ---------------- persistent weight fragments (VGPR-resident, bf16) -------
  bf16x8 wf0[4][6], wf1[3][6], wf2[2][5], wfc[2];
  {
    // L0: 32 units = 8 Ntiles x 4 mats (ff1,ff2,ta,tb); masked mats 0,1
    #pragma unroll
    for (int i = 0; i < 4; ++i) {
      const int u = w + 8 * i, mat = u & 3, Nt = u >> 2;
      const float* __restrict__ W  = args.in[1 + 2 * mat];
      const float* __restrict__ Mk = args.in[0];
      const int n = Nt * 16 + nl;
      #pragma unroll
      for (int kt = 0; kt < 6; ++kt) {
        bf16x8 f;
        #pragma unroll
        for (int j = 0; j < 8; ++j) {
          const int k = kt * 32 + kb + j;
          float v = 0.f;
          if (n < H_0 && k < CAT_0) {
            v = W[n * CAT_0 + k];
            if (mat < 2) v *= Mk[n * CAT_0 + k];
          }
          f[j] = (__bf16)v;
        }
        wf0[i][kt] = f;
      }
    }
    // L1: 20 units
    #pragma unroll
    for (int i = 0; i < 3; ++i) {
      const int u = w + 8 * i, mat = u & 3, Nt = u >> 2;
      const bool valid = u < 20;
      const float* __restrict__ W  = args.in[10 + 2 * mat];
      const float* __restrict__ Mk = args.in[9];
      const int n = Nt * 16 + nl;
      #pragma unroll
      for (int kt = 0; kt < 6; ++kt) {
        bf16x8 f;
        #pragma unroll
        for (int j = 0; j < 8; ++j) {
          const int k = kt * 32 + kb + j;
          float v = 0.f;
          if (valid && n < H_1 && k < CAT_1) {
            v = W[n * CAT_1 + k];
            if (mat < 2) v *= Mk[n * CAT_1 + k];
          }
          f[j] = (__bf16)v;
        }
        wf1[i][kt] = f;
      }
    }
    // L2: 16 units (n < 64 always valid)
    #pragma unroll
    for (int i = 0; i < 2; ++i) {
      const int u = w + 8 * i, mat = u & 3, Nt = u >> 2;
      const float* __restrict__ W  = args.in[19 + 2 * mat];
      const float* __restrict__ Mk = args.in[18];
      const int n = Nt * 16 + nl;
      #pragma unroll
      for (int kt = 0; kt < 5; ++kt) {
        bf16x8 f;
        #pragma unroll
        for (int j = 0; j < 8; ++j) {
          const int k = kt * 32 + kb + j;
          float v = 0.f;
          if (k < CAT_2) {
            v = W[n * CAT_2 + k];
            if (mat < 2) v *= Mk[n * CAT_2 + k];
          }
          f[j] = (__bf16)v;
        }
        wf2[i][kt] = f;
      }
    }
    // FC weights: waves 4..7 own o-tile (w-4); A[o][k=n]
    if (w >= 4) {
      const int ot = w - 4;
      #pragma unroll
      for (int kt = 0; kt < 2; ++kt) {
        bf16x8 f;
        #pragma unroll
        for (int j = 0; j < 8; ++j) {
          const int k = kt * 32 + kb + j;
          f[j] = (__bf16)args.in[27][(ot * 16 + nl) * 64 + k];
        }
        wfc[kt] = f;
      }
    } else {
      #pragma unroll
      for (int kt = 0; kt < 2; ++kt) {
        bf16x8 f;
        #pragma unroll
        for (int j = 0; j < 8; ++j) f[j] = (__bf16)0.f;
        wfc[kt] = f;
      }
    }
  }

  // ---------------- LDS init: zero cats (h0=0 + K pads), biases -------------
  for (int idx = tid; idx < 16 * LD_0; idx += NTH) { s_c0h[idx] = (__bf16)0.f; s_c0l[idx] = (__bf16)0.f; }
  for (int idx = tid; idx < 16 * LD_1; idx += NTH) { s_c1h[idx] = (__bf16)0.f; s_c1l[idx] = (__bf16)0.f; }
  for (int idx = tid; idx < 16 * LD_2; idx += NTH) { s_c2h[idx] = (__bf16)0.f; s_c2l[idx] = (__bf16)0.f; }
  #pragma unroll
  for (int m = 0; m < 4; ++m) {
    if (tid < 128) s_b0[m * 128 + tid] = (tid < H_0) ? args.in[2 + 2 * m][tid] : 0.f;
    if (tid < 80)  s_b1[m * 80 + tid]  = (tid < H_1) ? args.in[11 + 2 * m][tid] : 0.f;
    if (tid < 64)  s_b2[m * 64 + tid]  = args.in[20 + 2 * m][tid];
  }
  if (tid < 64) s_bfc[tid] = args.in[28][tid];
  __syncthreads();

  // prefetch x(t=0): thread covers 2 of the 16x64 values
  float xr[2];
  #pragma unroll
  for (int i = 0; i < 2; ++i) {
    const int v = tid + i * NTH;
    const int r = v >> 6, c = v & 63;
    xr[i] = xg[((size_t)(wgBase + r) * SEQT + 0) * 64 + c];
  }

  // ---------------- main recurrence ----------------------------------------
  #pragma unroll 1
  for (int t = 0; t < SEQT; ++t) {
    // X: x_t -> cat0[:, 0:64) hi/lo
    #pragma unroll
    for (int i = 0; i < 2; ++i) {
      const int v = tid + i * NTH;
      const int r = v >> 6, c = v & 63;
      const float val = xr[i];
      const __bf16 hh = (__bf16)val;
      s_c0h[r * LD_0 + c] = hh;
      s_c0l[r * LD_0 + c] = (__bf16)(val - (float)hh);
    }
    __syncthreads();

    // prefetch x(t+1); issued here so the barrier drain lands after M0's work
    {
      const int tn = (t + 1 < SEQT) ? (t + 1) : t;
      #pragma unroll
      for (int i = 0; i < 2; ++i) {
        const int v = tid + i * NTH;
        const int r = v >> 6, c = v & 63;
        xr[i] = xg[((size_t)(wgBase + r) * SEQT + tn) * 64 + c];
      }
    }

    // M0
    mfma_phase<4, 6, LD_0>(s_c0h, s_c0l, wf0, s_sums, w, lane, 32);
    __syncthreads();

    // C0: h0' -> cat1[:,0:116) and cat0[:,64:180)
    #pragma unroll
    for (int i = 0; i < 4; ++i) {
      const int v = tid + i * NTH;
      const int n = v >> 4, r = v & 15;
      if (n < H_0) {
        const float h = cfc_combine(s_sums, s_b0, n, r, 128);
        const __bf16 hh = (__bf16)h;
        const __bf16 hl = (__bf16)(h - (float)hh);
        s_c1h[r * LD_1 + n] = hh;       s_c1l[r * LD_1 + n] = hl;
        s_c0h[r * LD_0 + 64 + n] = hh;  s_c0l[r * LD_0 + 64 + n] = hl;
      }
    }
    __syncthreads();

    // M1
    mfma_phase<3, 6, LD_1>(s_c1h, s_c1l, wf1, s_sums, w, lane, 20);
    __syncthreads();

    // C1: h1' -> cat2[:,0:76) and cat1[:,116:192)
    #pragma unroll
    for (int i = 0; i < 3; ++i) {
      const int v = tid + i * NTH;
      if (v < 16 * 80) {
        const int n = v >> 4, r = v & 15;
        if (n < H_1) {
          const float h = cfc_combine(s_sums, s_b1, n, r, 80);
          const __bf16 hh = (__bf16)h;
          const __bf16 hl = (__bf16)(h - (float)hh);
          s_c2h[r * LD_2 + n] = hh;        s_c2l[r * LD_2 + n] = hl;
          s_c1h[r * LD_1 + 116 + n] = hh;  s_c1l[r * LD_1 + 116 + n] = hl;
        }
      }
    }
    __syncthreads();

    // M2
    mfma_phase<2, 5, LD_2>(s_c2h, s_c2l, wf2, s_sums, w, lane, 16);
    __syncthreads();

    // C2: h2' (motor) -> cat2[:,76:140) and FC input buffers
    #pragma unroll
    for (int i = 0; i < 2; ++i) {
      const int v = tid + i * NTH;
      const int n = v >> 4, r = v & 15;
      const float h = cfc_combine(s_sums, s_b2, n, r, 64);
      const __bf16 hh = (__bf16)h;
      const __bf16 hl = (__bf16)(h - (float)hh);
      s_c2h[r * LD_2 + 76 + n] = hh;  s_c2l[r * LD_2 + 76 + n] = hl;
      s_mh[r * LD_M + n] = hh;        s_ml[r * LD_M + n] = hl;
    }
    __syncthreads();

    // FC (waves 4..7): y[o][r] = sum_n wfc[o][n]*h2[r][n] + b_fc
    if (w >= 4) {
      f32x4 acc = {0.f, 0.f, 0.f, 0.f};
      #pragma unroll
      for (int kt = 0; kt < 2; ++kt) {
        const bf16x8 mh = *reinterpret_cast<const bf16x8*>(s_mh + nl * LD_M + kt * 32 + kb);
        const bf16x8 ml = *reinterpret_cast<const bf16x8*>(s_ml + nl * LD_M + kt * 32 + kb);
        acc = __builtin_amdgcn_mfma_f32_16x16x32_bf16(wfc[kt], mh, acc, 0, 0, 0);
        acc = __builtin_amdgcn_mfma_f32_16x16x32_bf16(wfc[kt], ml, acc, 0, 0, 0);
      }
      const int ot = w - 4;
      #pragma unroll
      for (int q = 0; q < 4; ++q) {
        const int o = ot * 16 + (lane >> 4) * 4 + q;
        out[((size_t)(wgBase + nl) * SEQT + t) * 64 + o] = acc[q] + s_bfc[o];
      }
    }
    // no barrier: next iteration's X-phase barrier orders FC's s_mh reads
    // against the next C2 rewrite (6 barriers away).
  }
}

extern "C" void kernel_launch(void* const* d_in, const int* in_sizes, int n_in,
                              void* d_out, int out_size, void* d_ws, size_t ws_size,
                              hipStream_t stream) {
  KArgs args;
  for (int i = 0; i < 30; ++i) args.in[i] = (const float*)d_in[i];
  args.out = (float*)d_out;
  ncp_fused<<<dim3(32), dim3(NTH), 0, stream>>>(args);
}

// Round 2
// 1272.959 us; speedup vs baseline: 2.0137x; 2.0137x over previous
//
#include <hip/hip_runtime.h>

typedef __bf16 bf16x8 __attribute__((ext_vector_type(8)));
typedef __bf16 bf16x4 __attribute__((ext_vector_type(4)));
typedef float f32x4 __attribute__((ext_vector_type(4)));

#define NTH  512
#define SEQT 256
#define H0 116
#define H1 76
// LDS leading dims (bf16): chosen so row-stride in dwords mod 32 is 4*odd -> clean b128 reads
#define LD0 200
#define LD1 200
#define LD2 168

struct KArgs { const float* in[30]; float* out; };

__device__ __forceinline__ float fast_tanh(float x) {
  return __fdividef(2.0f, 1.0f + __expf(-2.0f * x)) - 1.0f;
}
__device__ __forceinline__ float fast_sig(float x) {
  return __fdividef(1.0f, 1.0f + __expf(-x));
}

__device__ __forceinline__ f32x4 mfma2(bf16x8 a, bf16x8 bh, bf16x8 bl, f32x4 acc) {
  acc = __builtin_amdgcn_mfma_f32_16x16x32_bf16(a, bh, acc, 0, 0, 0);
  acc = __builtin_amdgcn_mfma_f32_16x16x32_bf16(a, bl, acc, 0, 0, 0);
  return acc;
}

// MFMA over KT k-tiles of one cat buffer; 4 mats share each B-fragment pair.
template<int KT>
__device__ __forceinline__ void run_part(f32x4 acc[4], const bf16x8* wf, int mstride, int kt0,
                                         const __bf16* __restrict__ ch, const __bf16* __restrict__ cl,
                                         int LD, int r, int kb) {
  #pragma unroll
  for (int kt = 0; kt < KT; ++kt) {
    const bf16x8 bh = *reinterpret_cast<const bf16x8*>(ch + r * LD + kt * 32 + kb);
    const bf16x8 bl = *reinterpret_cast<const bf16x8*>(cl + r * LD + kt * 32 + kb);
    #pragma unroll
    for (int m = 0; m < 4; ++m)
      acc[m] = mfma2(wf[m * mstride + kt0 + kt], bh, bl, acc[m]);
  }
}

// bias preload into MFMA C-in (4 consecutive n -> one b128)
__device__ __forceinline__ void init_acc(f32x4 acc[4], const float* __restrict__ sb, int bstride, int n0) {
  #pragma unroll
  for (int m = 0; m < 4; ++m)
    acc[m] = *reinterpret_cast<const f32x4*>(sb + m * bstride + n0);
}

__device__ __forceinline__ void combine_vals(const f32x4 acc[4], bf16x4* vh, bf16x4* vl) {
  #pragma unroll
  for (int q = 0; q < 4; ++q) {
    const float ff1 = fast_tanh(acc[0][q]);
    const float ff2 = fast_tanh(acc[1][q]);
    const float ti  = fast_sig(acc[2][q] + acc[3][q]);
    const float h   = ff1 + ti * (ff2 - ff1);
    const __bf16 hh = (__bf16)h;
    (*vh)[q] = hh;
    (*vl)[q] = (__bf16)(h - (float)hh);
  }
}

__device__ __forceinline__ bf16x8 load_b16x8_2x4(const __bf16* p) {  // 8B-aligned 16B read
  const bf16x4 a = *reinterpret_cast<const bf16x4*>(p);
  const bf16x4 b = *reinterpret_cast<const bf16x4*>(p + 4);
  bf16x8 v;
  v[0]=a[0]; v[1]=a[1]; v[2]=a[2]; v[3]=a[3];
  v[4]=b[0]; v[5]=b[1]; v[6]=b[2]; v[7]=b[3];
  return v;
}

__global__ __launch_bounds__(NTH, 2) void ncp_fused(KArgs args) {
  // double-buffered cat buffers (parity t&1), bf16 hi/lo
  __shared__ __align__(16) __bf16 s_c0h[2][16 * LD0], s_c0l[2][16 * LD0];
  __shared__ __align__(16) __bf16 s_c1h[2][16 * LD1], s_c1l[2][16 * LD1];
  __shared__ __align__(16) __bf16 s_c2h[2][16 * LD2], s_c2l[2][16 * LD2];
  __shared__ __align__(16) __bf16 s_w2[80 * 64 * 8];   // L2 weight frags: ((tile*4+m)*5+kt)*64+lane, 8 bf16 each
  __shared__ float s_b0[4 * 128], s_b1[4 * 80], s_b2[4 * 64];

  const int tid  = threadIdx.x;
  const int w    = tid >> 6;
  const int lane = tid & 63;
  const int r    = lane & 15;       // batch row (B-frag col / C col)
  const int g    = lane >> 4;
  const int kb   = g * 8;
  const int n0   = w * 16 + 4 * g;  // unused meaningfully per phase; recomputed below
  const int wgBase = blockIdx.x * 16;
  const float* __restrict__ xg = args.in[29];
  float* __restrict__ out = args.out;
  (void)n0;

  // ---------- resident weight fragments: L0 tile w, L1 tile w (w<5), FC otile w (w<4) ----------
  bf16x8 wA[24], wB[24], wfc[2];
  {
    const int n = w * 16 + r;   // A-frag row = lane&15
    const float* __restrict__ Mk = args.in[0];
    #pragma unroll
    for (int m = 0; m < 4; ++m) {
      const float* __restrict__ W = args.in[1 + 2 * m];
      #pragma unroll
      for (int kt = 0; kt < 6; ++kt) {
        bf16x8 f;
        #pragma unroll
        for (int j = 0; j < 8; ++j) {
          const int k = kt * 32 + kb + j;
          float v = 0.f;
          if (n < H0 && k < 180) { v = W[n * 180 + k]; if (m < 2) v *= Mk[n * 180 + k]; }
          f[j] = (__bf16)v;
        }
        wA[m * 6 + kt] = f;
      }
    }
  }
  {
    const int n = w * 16 + r;
    const bool tv = (w < 5);
    const float* __restrict__ Mk = args.in[9];
    #pragma unroll
    for (int m = 0; m < 4; ++m) {
      const float* __restrict__ W = args.in[10 + 2 * m];
      #pragma unroll
      for (int kt = 0; kt < 6; ++kt) {
        bf16x8 f;
        #pragma unroll
        for (int j = 0; j < 8; ++j) {
          const int k = kt * 32 + kb + j;
          float v = 0.f;
          if (tv && n < H1) { v = W[n * 192 + k]; if (m < 2) v *= Mk[n * 192 + k]; }
          f[j] = (__bf16)v;
        }
        wB[m * 6 + kt] = f;
      }
    }
  }
  f32x4 bfc = {0.f, 0.f, 0.f, 0.f};
  {
    #pragma unroll
    for (int kt = 0; kt < 2; ++kt) {
      bf16x8 f;
      #pragma unroll
      for (int j = 0; j < 8; ++j) {
        float v = 0.f;
        if (w < 4) v = args.in[27][(w * 16 + r) * 64 + kt * 32 + kb + j];
        f[j] = (__bf16)v;
      }
      wfc[kt] = f;
    }
    if (w < 4) {
      #pragma unroll
      for (int q = 0; q < 4; ++q) bfc[q] = args.in[28][w * 16 + 4 * g + q];
    }
  }

  // ---------- LDS fills ----------
  // L2 weight frags (masked mats 0,1; k>=140 zero-padded)
  for (int u = tid; u < 80 * 64; u += NTH) {
    const int ln = u & 63;
    const int ff = u >> 6;             // (tile*4+m)*5+kt
    const int kt = ff % 5;
    const int m  = (ff / 5) & 3;
    const int tile = ff / 20;
    const int n  = tile * 16 + (ln & 15);
    const int kbb = (ln >> 4) * 8;
    const float* __restrict__ W  = args.in[19 + 2 * m];
    const float* __restrict__ Mk = args.in[18];
    bf16x8 f;
    #pragma unroll
    for (int j = 0; j < 8; ++j) {
      const int k = kt * 32 + kbb + j;
      float v = 0.f;
      if (k < 140) { v = W[n * 140 + k]; if (m < 2) v *= Mk[n * 140 + k]; }
      f[j] = (__bf16)v;
    }
    *reinterpret_cast<bf16x8*>(s_w2 + (size_t)u * 8) = f;
  }
  // biases (padded with zeros)
  { const int m = tid >> 7, n = tid & 127; s_b0[tid] = (n < H0) ? args.in[2 + 2 * m][n] : 0.f; }
  if (tid < 4 * 80) { const int m = tid / 80, n = tid % 80; s_b1[tid] = (n < H1) ? args.in[11 + 2 * m][n] : 0.f; }
  if (tid < 4 * 64) { const int m = tid >> 6, n = tid & 63; s_b2[tid] = args.in[20 + 2 * m][n]; }
  // zero both parities of all cat buffers (h(-1)=0 and K pads)
  for (int i = tid; i < 2 * 16 * LD0; i += NTH) { s_c0h[0][i] = (__bf16)0.f; s_c0l[0][i] = (__bf16)0.f; }
  for (int i = tid; i < 2 * 16 * LD1; i += NTH) { s_c1h[0][i] = (__bf16)0.f; s_c1l[0][i] = (__bf16)0.f; }
  for (int i = tid; i < 2 * 16 * LD2; i += NTH) { s_c2h[0][i] = (__bf16)0.f; s_c2l[0][i] = (__bf16)0.f; }
  __syncthreads();
  // x(0) -> c0[0][:, 0:64)
  #pragma unroll
  for (int i = 0; i < 2; ++i) {
    const int rr = (i == 0) ? (tid >> 6) : (8 + (tid >> 6));
    const int c  = tid & 63;
    const float val = xg[((size_t)(wgBase + rr) * SEQT + 0) * 64 + c];
    const __bf16 hh = (__bf16)val;
    s_c0h[0][rr * LD0 + c] = hh;
    s_c0l[0][rr * LD0 + c] = (__bf16)(val - (float)hh);
  }
  __syncthreads();

  // ---------- recurrence: 3 barriers / step ----------
  float xr0, xr1;
  #pragma unroll 1
  for (int t = 0; t < SEQT; ++t) {
    const int cur = t & 1, nxt = cur ^ 1;

    // prefetch x(t+1) (consumed in phase 3)
    {
      const int tn = (t + 1 < SEQT) ? t + 1 : t;
      xr0 = xg[((size_t)(wgBase + (tid >> 6)) * SEQT + tn) * 64 + (tid & 63)];
      xr1 = xg[((size_t)(wgBase + 8 + (tid >> 6)) * SEQT + tn) * 64 + (tid & 63)];
    }

    // ---- Phase 1: layer 0 (all 8 waves, tile w). reads c0[cur]; writes c1[cur][0:116), c0[nxt][64:180)
    {
      f32x4 acc[4];
      const int nb = w * 16 + 4 * g;
      init_acc(acc, s_b0, 128, nb);
      run_part<6>(acc, wA, 6, 0, s_c0h[cur], s_c0l[cur], LD0, r, kb);
      if (nb < H0) {
        bf16x4 vh, vl;
        combine_vals(acc, &vh, &vl);
        *reinterpret_cast<bf16x4*>(s_c1h[cur] + r * LD1 + nb)      = vh;
        *reinterpret_cast<bf16x4*>(s_c1l[cur] + r * LD1 + nb)      = vl;
        *reinterpret_cast<bf16x4*>(s_c0h[nxt] + r * LD0 + 64 + nb) = vh;
        *reinterpret_cast<bf16x4*>(s_c0l[nxt] + r * LD0 + 64 + nb) = vl;
      }
    }
    __syncthreads();

    // ---- Phase 2: layer 1 (waves 0..4). reads c1[cur]; writes c2[cur][0:76), c1[nxt][116:192)
    if (w < 5) {
      f32x4 acc[4];
      const int nb = w * 16 + 4 * g;
      init_acc(acc, s_b1, 80, nb);
      run_part<6>(acc, wB, 6, 0, s_c1h[cur], s_c1l[cur], LD1, r, kb);
      if (nb < H1) {
        bf16x4 vh, vl;
        combine_vals(acc, &vh, &vl);
        *reinterpret_cast<bf16x4*>(s_c2h[cur] + r * LD2 + nb)       = vh;
        *reinterpret_cast<bf16x4*>(s_c2l[cur] + r * LD2 + nb)       = vl;
        *reinterpret_cast<bf16x4*>(s_c1h[nxt] + r * LD1 + 116 + nb) = vh;
        *reinterpret_cast<bf16x4*>(s_c1l[nxt] + r * LD1 + 116 + nb) = vl;
      }
    }
    __syncthreads();

    // ---- Phase 3: layer 2 on waves 4..7 (tile w-4); FC(t-1) on waves 0..3; x(t+1) stage
    if (w >= 4) {
      f32x4 acc[4];
      const int tile = w - 4;
      const int nb = tile * 16 + 4 * g;
      init_acc(acc, s_b2, 64, nb);
      #pragma unroll
      for (int kt = 0; kt < 5; ++kt) {
        const bf16x8 bh = *reinterpret_cast<const bf16x8*>(s_c2h[cur] + r * LD2 + kt * 32 + kb);
        const bf16x8 bl = *reinterpret_cast<const bf16x8*>(s_c2l[cur] + r * LD2 + kt * 32 + kb);
        #pragma unroll
        for (int m = 0; m < 4; ++m) {
          const bf16x8 a = *reinterpret_cast<const bf16x8*>(s_w2 + (size_t)((((tile * 4 + m) * 5) + kt) * 64 + lane) * 8);
          acc[m] = mfma2(a, bh, bl, acc[m]);
        }
      }
      bf16x4 vh, vl;
      combine_vals(acc, &vh, &vl);
      *reinterpret_cast<bf16x4*>(s_c2h[nxt] + r * LD2 + 76 + nb) = vh;
      *reinterpret_cast<bf16x4*>(s_c2l[nxt] + r * LD2 + 76 + nb) = vl;
    } else if (t > 0) {
      // FC on h2(t-1) which lives in c2[cur][:, 76:140)
      f32x4 acc = bfc;
      #pragma unroll
      for (int kt = 0; kt < 2; ++kt) {
        const bf16x8 bh = load_b16x8_2x4(s_c2h[cur] + r * LD2 + 76 + kt * 32 + kb);
        const bf16x8 bl = load_b16x8_2x4(s_c2l[cur] + r * LD2 + 76 + kt * 32 + kb);
        acc = __builtin_amdgcn_mfma_f32_16x16x32_bf16(wfc[kt], bh, acc, 0, 0, 0);
        acc = __builtin_amdgcn_mfma_f32_16x16x32_bf16(wfc[kt], bl, acc, 0, 0, 0);
      }
      *reinterpret_cast<f32x4*>(out + ((size_t)(wgBase + r) * SEQT + (t - 1)) * 64 + w * 16 + 4 * g) = acc;
    }
    // stage x(t+1) into c0[nxt][:, 0:64)
    {
      const int rr = tid >> 6, c = tid & 63;
      const __bf16 h0_ = (__bf16)xr0;
      s_c0h[nxt][rr * LD0 + c] = h0_;
      s_c0l[nxt][rr * LD0 + c] = (__bf16)(xr0 - (float)h0_);
      const __bf16 h1_ = (__bf16)xr1;
      s_c0h[nxt][(8 + rr) * LD0 + c] = h1_;
      s_c0l[nxt][(8 + rr) * LD0 + c] = (__bf16)(xr1 - (float)h1_);
    }
    __syncthreads();
  }

  // ---------- epilogue: FC for t = 255; h2(255) is in c2[(255+1)&1] = c2[0]
  if (w < 4) {
    f32x4 acc = bfc;
    #pragma unroll
    for (int kt = 0; kt < 2; ++kt) {
      const bf16x8 bh = load_b16x8_2x4(s_c2h[0] + r * LD2 + 76 + kt * 32 + kb);
      const bf16x8 bl = load_b16x8_2x4(s_c2l[0] + r * LD2 + 76 + kt * 32 + kb);
      acc = __builtin_amdgcn_mfma_f32_16x16x32_bf16(wfc[kt], bh, acc, 0, 0, 0);
      acc = __builtin_amdgcn_mfma_f32_16x16x32_bf16(wfc[kt], bl, acc, 0, 0, 0);
    }
    *reinterpret_cast<f32x4*>(out + ((size_t)(wgBase + r) * SEQT + 255) * 64 + w * 16 + 4 * g) = acc;
  }
}

extern "C" void kernel_launch(void* const* d_in, const int* in_sizes, int n_in,
                              void* d_out, int out_size, void* d_ws, size_t ws_size,
                              hipStream_t stream) {
  KArgs args;
  for (int i = 0; i < 30; ++i) args.in[i] = (const float*)d_in[i];
  args.out = (float*)d_out;
  ncp_fused<<<dim3(32), dim3(NTH), 0, stream>>>(args);
}

// Round 3
// 1004.921 us; speedup vs baseline: 2.5508x; 1.2667x over previous
//
#include <hip/hip_runtime.h>

typedef _Float16 f16x8 __attribute__((ext_vector_type(8)));
typedef _Float16 f16x4 __attribute__((ext_vector_type(4)));
typedef float f32x4 __attribute__((ext_vector_type(4)));

#define NTH  512
#define SEQT 256
#define H0 116
#define H1 76
// LDS leading dims in halfs; stride%64==8 -> row bank-quads cycle cleanly for b128
#define LD0 200
#define LD1 200
#define LD2 168

struct KArgs { const float* in[30]; float* out; };

__device__ __forceinline__ float fast_tanh(float x) {
  return __fdividef(2.0f, 1.0f + __expf(-2.0f * x)) - 1.0f;
}
__device__ __forceinline__ float fast_sig(float x) {
  return __fdividef(1.0f, 1.0f + __expf(-x));
}

__device__ __forceinline__ void combine4(const f32x4 acc[4], f16x4* v) {
  #pragma unroll
  for (int q = 0; q < 4; ++q) {
    const float ff1 = fast_tanh(acc[0][q]);
    const float ff2 = fast_tanh(acc[1][q]);
    const float ti  = fast_sig(acc[2][q] + acc[3][q]);
    (*v)[q] = (_Float16)(ff1 + ti * (ff2 - ff1));
  }
}

__device__ __forceinline__ void init_acc(f32x4 acc[4], const float* __restrict__ sb,
                                         int bstride, int n0) {
  #pragma unroll
  for (int m = 0; m < 4; ++m)
    acc[m] = *reinterpret_cast<const f32x4*>(sb + m * bstride + n0);
}

// KT k-tiles of one fp16 cat buffer; 4 mats share each B-fragment. wf stride fixed 6.
template<int KT>
__device__ __forceinline__ void run_part(f32x4 acc[4], const f16x8* wf,
                                         const _Float16* __restrict__ c,
                                         int LD, int r, int kb) {
  #pragma unroll
  for (int kt = 0; kt < KT; ++kt) {
    const f16x8 b = *reinterpret_cast<const f16x8*>(c + r * LD + kt * 32 + kb);
    #pragma unroll
    for (int m = 0; m < 4; ++m)
      acc[m] = __builtin_amdgcn_mfma_f32_16x16x32_f16(wf[m * 6 + kt], b, acc[m], 0, 0, 0);
  }
}

__device__ __forceinline__ f16x8 load_f16x8_2x4(const _Float16* p) {  // 8B-aligned 16B
  const f16x4 a = *reinterpret_cast<const f16x4*>(p);
  const f16x4 b = *reinterpret_cast<const f16x4*>(p + 4);
  f16x8 v;
  v[0]=a[0]; v[1]=a[1]; v[2]=a[2]; v[3]=a[3];
  v[4]=b[0]; v[5]=b[1]; v[6]=b[2]; v[7]=b[3];
  return v;
}

__global__ __launch_bounds__(NTH, 2) void ncp_fused(KArgs args) {
  // double-buffered fp16 cat buffers (parity t&1)
  __shared__ __align__(16) _Float16 s_c0[2][16 * LD0];
  __shared__ __align__(16) _Float16 s_c1[2][16 * LD1];
  __shared__ __align__(16) _Float16 s_c2[2][16 * LD2];
  __shared__ __align__(16) _Float16 s_w23[20 * 64 * 8];  // L2 tile-3 frags for wave 7
  __shared__ float s_b0[4 * 128], s_b1[4 * 80], s_b2[4 * 64];

  const int tid  = threadIdx.x;
  const int w    = tid >> 6;
  const int lane = tid & 63;
  const int r    = lane & 15;       // batch row
  const int g    = lane >> 4;
  const int kb   = g * 8;
  const int wgBase = blockIdx.x * 16;
  const float* __restrict__ xg = args.in[29];
  float* __restrict__ out = args.out;

  // ---------- resident weight fragments ----------
  // wA: L0 tile w (all waves). wX: union -> L1 tile {w or 4} for waves {0..3,7},
  // L2 tile (w-4) for waves {4,5,6}. Wave 7's L2 tile 3 lives in LDS (s_w23).
  f16x8 wA[24], wX[24], wfc[2];
  {
    const int n = w * 16 + r;
    const float* __restrict__ Mk = args.in[0];
    #pragma unroll
    for (int m = 0; m < 4; ++m) {
      const float* __restrict__ W = args.in[1 + 2 * m];
      #pragma unroll
      for (int kt = 0; kt < 6; ++kt) {
        f16x8 f;
        #pragma unroll
        for (int j = 0; j < 8; ++j) {
          const int k = kt * 32 + kb + j;
          float v = 0.f;
          if (n < H0 && k < 180) { v = W[n * 180 + k]; if (m < 2) v *= Mk[n * 180 + k]; }
          f[j] = (_Float16)v;
        }
        wA[m * 6 + kt] = f;
      }
    }
  }
  if (w < 4 || w == 7) {             // L1 weights
    const int tl = (w == 7) ? 4 : w;
    const int n = tl * 16 + r;
    const float* __restrict__ Mk = args.in[9];
    #pragma unroll
    for (int m = 0; m < 4; ++m) {
      const float* __restrict__ W = args.in[10 + 2 * m];
      #pragma unroll
      for (int kt = 0; kt < 6; ++kt) {
        f16x8 f;
        #pragma unroll
        for (int j = 0; j < 8; ++j) {
          const int k = kt * 32 + kb + j;
          float v = 0.f;
          if (n < H1) { v = W[n * 192 + k]; if (m < 2) v *= Mk[n * 192 + k]; }
          f[j] = (_Float16)v;
        }
        wX[m * 6 + kt] = f;
      }
    }
  } else {                            // L2 weights, tiles 0..2
    const int n = (w - 4) * 16 + r;
    const float* __restrict__ Mk = args.in[18];
    #pragma unroll
    for (int m = 0; m < 4; ++m) {
      const float* __restrict__ W = args.in[19 + 2 * m];
      #pragma unroll
      for (int kt = 0; kt < 6; ++kt) {
        f16x8 f;
        #pragma unroll
        for (int j = 0; j < 8; ++j) {
          const int k = kt * 32 + kb + j;
          float v = 0.f;
          if (kt < 5 && k < 140) { v = W[n * 140 + k]; if (m < 2) v *= Mk[n * 140 + k]; }
          f[j] = (_Float16)v;
        }
        wX[m * 6 + kt] = f;
      }
    }
  }
  f32x4 bfc = {0.f, 0.f, 0.f, 0.f};
  {
    #pragma unroll
    for (int kt = 0; kt < 2; ++kt) {
      f16x8 f;
      #pragma unroll
      for (int j = 0; j < 8; ++j) {
        float v = 0.f;
        if (w < 4) v = args.in[27][(w * 16 + r) * 64 + kt * 32 + kb + j];
        f[j] = (_Float16)v;
      }
      wfc[kt] = f;
    }
    if (w < 4) {
      #pragma unroll
      for (int q = 0; q < 4; ++q) bfc[q] = args.in[28][w * 16 + 4 * g + q];
    }
  }

  // ---------- LDS fills ----------
  // L2 tile-3 frags (for wave 7): ((m*5+kt)*64+lane)*8
  for (int u = tid; u < 20 * 64; u += NTH) {
    const int ln = u & 63;
    const int ff = u >> 6;
    const int kt = ff % 5, m = ff / 5;
    const int n  = 48 + (ln & 15);
    const int kbb = (ln >> 4) * 8;
    const float* __restrict__ W  = args.in[19 + 2 * m];
    const float* __restrict__ Mk = args.in[18];
    f16x8 f;
    #pragma unroll
    for (int j = 0; j < 8; ++j) {
      const int k = kt * 32 + kbb + j;
      float v = 0.f;
      if (k < 140) { v = W[n * 140 + k]; if (m < 2) v *= Mk[n * 140 + k]; }
      f[j] = (_Float16)v;
    }
    *reinterpret_cast<f16x8*>(s_w23 + (size_t)u * 8) = f;
  }
  // biases (zero-padded)
  { const int m = tid >> 7, n = tid & 127; s_b0[tid] = (n < H0) ? args.in[2 + 2 * m][n] : 0.f; }
  if (tid < 4 * 80) { const int m = tid / 80, n = tid % 80; s_b1[tid] = (n < H1) ? args.in[11 + 2 * m][n] : 0.f; }
  if (tid < 4 * 64) { const int m = tid >> 6, n = tid & 63; s_b2[tid] = args.in[20 + 2 * m][n]; }
  // zero both parities (h(-1)=0 and K pads stay zero forever)
  for (int i = tid; i < 2 * 16 * LD0; i += NTH) s_c0[0][i] = (_Float16)0.f;
  for (int i = tid; i < 2 * 16 * LD1; i += NTH) s_c1[0][i] = (_Float16)0.f;
  for (int i = tid; i < 2 * 16 * LD2; i += NTH) s_c2[0][i] = (_Float16)0.f;
  __syncthreads();
  // x(0) -> c0[0][:, 0:64)
  #pragma unroll
  for (int i = 0; i < 2; ++i) {
    const int rr = (i == 0) ? (tid >> 6) : (8 + (tid >> 6));
    const int c  = tid & 63;
    s_c0[0][rr * LD0 + c] = (_Float16)xg[((size_t)(wgBase + rr) * SEQT + 0) * 64 + c];
  }
  __syncthreads();

  // ---------- recurrence: 3 barriers / step ----------
  float xr0, xr1;
  #pragma unroll 1
  for (int t = 0; t < SEQT; ++t) {
    const int cur = t & 1, nxt = cur ^ 1;

    // prefetch x(t+1); consumed at end of phase 3 (two barriers of latency hiding)
    {
      const int tn = (t + 1 < SEQT) ? t + 1 : t;
      xr0 = xg[((size_t)(wgBase + (tid >> 6)) * SEQT + tn) * 64 + (tid & 63)];
      xr1 = xg[((size_t)(wgBase + 8 + (tid >> 6)) * SEQT + tn) * 64 + (tid & 63)];
    }

    // ---- Phase 1: layer 0, all 8 waves (tile w)
    {
      f32x4 acc[4];
      const int nb = w * 16 + 4 * g;
      init_acc(acc, s_b0, 128, nb);
      run_part<6>(acc, wA, s_c0[cur], LD0, r, kb);
      if (nb < H0) {
        f16x4 v;
        combine4(acc, &v);
        *reinterpret_cast<f16x4*>(s_c1[cur] + r * LD1 + nb)      = v;
        *reinterpret_cast<f16x4*>(s_c0[nxt] + r * LD0 + 64 + nb) = v;
      }
    }
    __syncthreads();

    // ---- Phase 2: layer 1, waves {0,1,2,3,7} (tile w or 4)
    if (w < 4 || w == 7) {
      const int tl = (w == 7) ? 4 : w;
      f32x4 acc[4];
      const int nb = tl * 16 + 4 * g;
      init_acc(acc, s_b1, 80, nb);
      run_part<6>(acc, wX, s_c1[cur], LD1, r, kb);
      if (nb < H1) {
        f16x4 v;
        combine4(acc, &v);
        *reinterpret_cast<f16x4*>(s_c2[cur] + r * LD2 + nb)       = v;
        *reinterpret_cast<f16x4*>(s_c1[nxt] + r * LD1 + 116 + nb) = v;
      }
    }
    __syncthreads();

    // ---- Phase 3: layer 2 on waves 4..7 (tile w-4); FC(t-1) on waves 0..3
    if (w >= 4) {
      f32x4 acc[4];
      const int nb = (w - 4) * 16 + 4 * g;
      init_acc(acc, s_b2, 64, nb);
      if (w < 7) {
        run_part<5>(acc, wX, s_c2[cur], LD2, r, kb);
      } else {
        #pragma unroll
        for (int kt = 0; kt < 5; ++kt) {
          const f16x8 b = *reinterpret_cast<const f16x8*>(s_c2[cur] + r * LD2 + kt * 32 + kb);
          #pragma unroll
          for (int m = 0; m < 4; ++m) {
            const f16x8 a = *reinterpret_cast<const f16x8*>(s_w23 + (size_t)(((m * 5 + kt) * 64) + lane) * 8);
            acc[m] = __builtin_amdgcn_mfma_f32_16x16x32_f16(a, b, acc[m], 0, 0, 0);
          }
        }
      }
      f16x4 v;
      combine4(acc, &v);
      *reinterpret_cast<f16x4*>(s_c2[nxt] + r * LD2 + 76 + nb) = v;
    } else if (t > 0) {
      // FC on h2(t-1), resident in c2[cur][:, 76:140)
      f32x4 acc = bfc;
      #pragma unroll
      for (int kt = 0; kt < 2; ++kt) {
        const f16x8 b = load_f16x8_2x4(s_c2[cur] + r * LD2 + 76 + kt * 32 + kb);
        acc = __builtin_amdgcn_mfma_f32_16x16x32_f16(wfc[kt], b, acc, 0, 0, 0);
      }
      *reinterpret_cast<f32x4*>(out + ((size_t)(wgBase + r) * SEQT + (t - 1)) * 64 + w * 16 + 4 * g) = acc;
    }
    // stage x(t+1) into c0[nxt][:, 0:64)
    {
      const int rr = tid >> 6, c = tid & 63;
      s_c0[nxt][rr * LD0 + c]       = (_Float16)xr0;
      s_c0[nxt][(8 + rr) * LD0 + c] = (_Float16)xr1;
    }
    __syncthreads();
  }

  // ---------- epilogue: FC for t=255; h2(255) is in c2[0]
  if (w < 4) {
    f32x4 acc = bfc;
    #pragma unroll
    for (int kt = 0; kt < 2; ++kt) {
      const f16x8 b = load_f16x8_2x4(s_c2[0] + r * LD2 + 76 + kt * 32 + kb);
      acc = __builtin_amdgcn_mfma_f32_16x16x32_f16(wfc[kt], b, acc, 0, 0, 0);
    }
    *reinterpret_cast<f32x4*>(out + ((size_t)(wgBase + r) * SEQT + 255) * 64 + w * 16 + 4 * g) = acc;
  }
}

extern "C" void kernel_launch(void* const* d_in, const int* in_sizes, int n_in,
                              void* d_out, int out_size, void* d_ws, size_t ws_size,
                              hipStream_t stream) {
  KArgs args;
  for (int i = 0; i < 30; ++i) args.in[i] = (const float*)d_in[i];
  args.out = (float*)d_out;
  ncp_fused<<<dim3(32), dim3(NTH), 0, stream>>>(args);
}

// Round 4
// 800.509 us; speedup vs baseline: 3.2022x; 1.2554x over previous
//
#include <hip/hip_runtime.h>

typedef _Float16 f16x8 __attribute__((ext_vector_type(8)));
typedef _Float16 f16x4 __attribute__((ext_vector_type(4)));
typedef float f32x4 __attribute__((ext_vector_type(4)));

#define NTH 512
#define SEQT 256
#define LD0 200
#define LD1 200
#define LD2 168

struct KArgs { const float* in[30]; float* out; };

__device__ __forceinline__ float fast_tanh(float x) {
  return __fdividef(2.0f, 1.0f + __expf(-2.0f * x)) - 1.0f;
}
__device__ __forceinline__ float fast_sig(float x) {
  return __fdividef(1.0f, 1.0f + __expf(-x));
}

__device__ __forceinline__ f32x4 mfma16(f16x8 a, f16x8 b, f32x4 c) {
  return __builtin_amdgcn_mfma_f32_16x16x32_f16(a, b, c, 0, 0, 0);
}

__device__ __forceinline__ f16x4 combine3(const f32x4 acc[3]) {
  f16x4 v;
  #pragma unroll
  for (int q = 0; q < 4; ++q) {
    const float ff1 = fast_tanh(acc[0][q]);
    const float ff2 = fast_tanh(acc[1][q]);
    const float ti  = fast_sig(acc[2][q]);
    v[q] = (_Float16)(ff1 + ti * (ff2 - ff1));
  }
  return v;
}

// load one 3-mat tile (ff1*mask, ff2*mask, ta+tb) into wW[BASE..BASE+3*KT)
template<int BASE, int KT>
__device__ __forceinline__ void load_tile(f16x8* wW, const float* W1, const float* W2,
                                          const float* Wa, const float* Wb,
                                          const float* Mk, int n, int CAT, int H, int kb) {
  #pragma unroll
  for (int kt = 0; kt < KT; ++kt) {
    #pragma unroll
    for (int m = 0; m < 3; ++m) {
      f16x8 f;
      #pragma unroll
      for (int j = 0; j < 8; ++j) {
        const int k = kt * 32 + kb + j;
        float v = 0.f;
        if (n < H && k < CAT) {
          if (m == 0)      v = W1[n*CAT+k] * Mk[n*CAT+k];
          else if (m == 1) v = W2[n*CAT+k] * Mk[n*CAT+k];
          else             v = Wa[n*CAT+k] + Wb[n*CAT+k];
        }
        f[j] = (_Float16)v;
      }
      wW[BASE + m*KT + kt] = f;
    }
  }
}

template<int KT>
__device__ __forceinline__ void loadB(f16x8* B, const _Float16* c, int LD, int r, int kb) {
  #pragma unroll
  for (int kt = 0; kt < KT; ++kt)
    B[kt] = *reinterpret_cast<const f16x8*>(c + r*LD + kt*32 + kb);
}

template<int BASE, int KT>
__device__ __forceinline__ void mma_tile(f32x4 acc[3], const f16x8* wW, const f16x8* B) {
  #pragma unroll
  for (int kt = 0; kt < KT; ++kt)
    #pragma unroll
    for (int m = 0; m < 3; ++m)
      acc[m] = mfma16(wW[BASE + m*KT + kt], B[kt], acc[m]);
}

__device__ __forceinline__ void init3(f32x4 acc[3], const float* sb, int bs, int n0) {
  #pragma unroll
  for (int m = 0; m < 3; ++m)
    acc[m] = *reinterpret_cast<const f32x4*>(sb + m*bs + n0);
}

__device__ __forceinline__ f16x8 loadB8u(const _Float16* p) {  // 8B-aligned 16B read
  const f16x4 a = *reinterpret_cast<const f16x4*>(p);
  const f16x4 b = *reinterpret_cast<const f16x4*>(p + 4);
  f16x8 v;
  v[0]=a[0]; v[1]=a[1]; v[2]=a[2]; v[3]=a[3];
  v[4]=b[0]; v[5]=b[1]; v[6]=b[2]; v[7]=b[3];
  return v;
}

__global__ __launch_bounds__(NTH, 2) void ncp_fused(KArgs args) {
  // double-buffered fp16 cat buffers (parity p&1)
  __shared__ __align__(16) _Float16 c0[2][16 * LD0];
  __shared__ __align__(16) _Float16 c1[2][16 * LD1];
  __shared__ __align__(16) _Float16 c2[2][16 * LD2];
  __shared__ __align__(16) _Float16 wt3[15 * 64 * 8];   // L2 tile-3 frags (wave 7)
  __shared__ float b0s[3 * 128], b1s[3 * 80], b2s[3 * 64];

  const int tid  = threadIdx.x;
  const int w    = tid >> 6;
  const int lane = tid & 63;
  const int r    = lane & 15;      // batch row
  const int g    = lane >> 4;
  const int kb   = g * 8;
  const int wgBase = blockIdx.x * 16;
  const float* __restrict__ xg = args.in[29];
  float* __restrict__ out = args.out;

  // ---------- persistent weight fragments (wW union per wave role) ----------
  // w0..w3: L0 tiles (2w)->[0..17], (2w+1)->[18..35]; FC tile w in wfc.
  // w4,w5 : L1 tiles 2(w-4)->[0..17], 2(w-4)+1->[18..35].
  // w6    : L1 t4 ->[0..17]; L2 t0 ->[18..32].
  // w7    : L2 t1 ->[0..14]; L2 t2 ->[15..29]; L2 t3 via LDS (wt3).
  f16x8 wW[36], wfc[2];
  f32x4 bfc = {0.f, 0.f, 0.f, 0.f};
  if (w < 4) {
    load_tile<0, 6>(wW, args.in[1], args.in[3], args.in[5], args.in[7], args.in[0],
                    (2*w)*16 + r, 180, 116, kb);
    load_tile<18, 6>(wW, args.in[1], args.in[3], args.in[5], args.in[7], args.in[0],
                     (2*w+1)*16 + r, 180, 116, kb);
    #pragma unroll
    for (int kt = 0; kt < 2; ++kt) {
      f16x8 f;
      #pragma unroll
      for (int j = 0; j < 8; ++j)
        f[j] = (_Float16)args.in[27][(w*16 + r)*64 + kt*32 + kb + j];
      wfc[kt] = f;
    }
    #pragma unroll
    for (int q = 0; q < 4; ++q) bfc[q] = args.in[28][w*16 + 4*g + q];
  } else if (w < 6) {
    load_tile<0, 6>(wW, args.in[10], args.in[12], args.in[14], args.in[16], args.in[9],
                    (2*(w-4))*16 + r, 192, 76, kb);
    load_tile<18, 6>(wW, args.in[10], args.in[12], args.in[14], args.in[16], args.in[9],
                     (2*(w-4)+1)*16 + r, 192, 76, kb);
  } else if (w == 6) {
    load_tile<0, 6>(wW, args.in[10], args.in[12], args.in[14], args.in[16], args.in[9],
                    64 + r, 192, 76, kb);
    load_tile<18, 5>(wW, args.in[19], args.in[21], args.in[23], args.in[25], args.in[18],
                     r, 140, 64, kb);
  } else {
    load_tile<0, 5>(wW, args.in[19], args.in[21], args.in[23], args.in[25], args.in[18],
                    16 + r, 140, 64, kb);
    load_tile<15, 5>(wW, args.in[19], args.in[21], args.in[23], args.in[25], args.in[18],
                     32 + r, 140, 64, kb);
  }

  // ---------- LDS init ----------
  // L2 tile-3 frags: [(m*5+kt)*64 + lane]*8
  for (int u = tid; u < 15 * 64; u += NTH) {
    const int ln = u & 63;
    const int ff = u >> 6;
    const int kt = ff % 5, m = ff / 5;
    const int n  = 48 + (ln & 15);
    const int kbb = (ln >> 4) * 8;
    f16x8 f;
    #pragma unroll
    for (int j = 0; j < 8; ++j) {
      const int k = kt*32 + kbb + j;
      float v = 0.f;
      if (k < 140) {
        if (m == 0)      v = args.in[19][n*140+k] * args.in[18][n*140+k];
        else if (m == 1) v = args.in[21][n*140+k] * args.in[18][n*140+k];
        else             v = args.in[23][n*140+k] + args.in[25][n*140+k];
      }
      f[j] = (_Float16)v;
    }
    *reinterpret_cast<f16x8*>(wt3 + (size_t)u * 8) = f;
  }
  // biases (3 rows each: ff1, ff2, ta+tb), zero-padded
  if (tid < 128) {
    b0s[tid]       = (tid < 116) ? args.in[2][tid] : 0.f;
    b0s[128 + tid] = (tid < 116) ? args.in[4][tid] : 0.f;
    b0s[256 + tid] = (tid < 116) ? args.in[6][tid] + args.in[8][tid] : 0.f;
  }
  if (tid < 80) {
    b1s[tid]      = (tid < 76) ? args.in[11][tid] : 0.f;
    b1s[80 + tid] = (tid < 76) ? args.in[13][tid] : 0.f;
    b1s[160 + tid]= (tid < 76) ? args.in[15][tid] + args.in[17][tid] : 0.f;
  }
  if (tid < 64) {
    b2s[tid]       = args.in[20][tid];
    b2s[64 + tid]  = args.in[22][tid];
    b2s[128 + tid] = args.in[24][tid] + args.in[26][tid];
  }
  // zero both parities (initial hidden states + K pads stay zero)
  for (int i = tid; i < 2 * 16 * LD0; i += NTH) c0[0][i] = (_Float16)0.f;
  for (int i = tid; i < 2 * 16 * LD1; i += NTH) c1[0][i] = (_Float16)0.f;
  for (int i = tid; i < 2 * 16 * LD2; i += NTH) c2[0][i] = (_Float16)0.f;
  __syncthreads();
  // stage x(0) -> c0[0][:, 0:64)
  {
    const int rr = tid >> 6, cc = tid & 63;
    c0[0][rr * LD0 + cc]       = (_Float16)xg[((size_t)(wgBase + rr) * SEQT + 0) * 64 + cc];
    c0[0][(8 + rr) * LD0 + cc] = (_Float16)xg[((size_t)(wgBase + 8 + rr) * SEQT + 0) * 64 + cc];
  }
  __syncthreads();

  // ---------- pipelined recurrence: ONE barrier per phase ----------
  // phase p computes: L0->h0(p), L1->h1(p-1), L2->h2(p-2), FC->y(p-3)
  #pragma unroll 1
  for (int p = 0; p < SEQT + 3; ++p) {
    const int cur = p & 1, nxt = cur ^ 1;

    // prefetch x(p+1) (stored to LDS at end of this phase)
    float xr0, xr1;
    {
      const int tn = (p + 1 < SEQT) ? p + 1 : SEQT - 1;
      xr0 = xg[((size_t)(wgBase + (tid >> 6)) * SEQT + tn) * 64 + (tid & 63)];
      xr1 = xg[((size_t)(wgBase + 8 + (tid >> 6)) * SEQT + tn) * 64 + (tid & 63)];
    }

    if (w < 4) {
      if (p >= 3) {  // FC on h2(p-3) in c2[cur][:, 76:140)
        f32x4 acc = bfc;
        #pragma unroll
        for (int kt = 0; kt < 2; ++kt) {
          const f16x8 b = loadB8u(c2[cur] + r * LD2 + 76 + kt * 32 + kb);
          acc = mfma16(wfc[kt], b, acc);
        }
        *reinterpret_cast<f32x4*>(out + ((size_t)(wgBase + r) * SEQT + (p - 3)) * 64 + w * 16 + 4 * g) = acc;
      }
      if (p < SEQT) {  // L0 tiles 2w, 2w+1
        f16x8 B[6]; loadB<6>(B, c0[cur], LD0, r, kb);
        f32x4 aA[3], aB[3];
        const int nA = (2 * w) * 16 + 4 * g;
        const int nB = (2 * w + 1) * 16 + 4 * g;
        init3(aA, b0s, 128, nA);
        init3(aB, b0s, 128, nB);
        mma_tile<0, 6>(aA, wW, B);
        mma_tile<18, 6>(aB, wW, B);
        const f16x4 vA = combine3(aA);
        const f16x4 vB = combine3(aB);
        *reinterpret_cast<f16x4*>(c1[nxt] + r * LD1 + nA)      = vA;
        *reinterpret_cast<f16x4*>(c0[nxt] + r * LD0 + 64 + nA) = vA;
        if (nB < 116) {
          *reinterpret_cast<f16x4*>(c1[nxt] + r * LD1 + nB)      = vB;
          *reinterpret_cast<f16x4*>(c0[nxt] + r * LD0 + 64 + nB) = vB;
        }
      }
    } else if (w < 6) {
      if (p >= 1 && p < SEQT + 1) {  // L1 tiles 2(w-4), 2(w-4)+1
        f16x8 B[6]; loadB<6>(B, c1[cur], LD1, r, kb);
        f32x4 aA[3], aB[3];
        const int nA = (2 * (w - 4)) * 16 + 4 * g;
        const int nB = (2 * (w - 4) + 1) * 16 + 4 * g;
        init3(aA, b1s, 80, nA);
        init3(aB, b1s, 80, nB);
        mma_tile<0, 6>(aA, wW, B);
        mma_tile<18, 6>(aB, wW, B);
        const f16x4 vA = combine3(aA);
        const f16x4 vB = combine3(aB);
        *reinterpret_cast<f16x4*>(c1[nxt] + r * LD1 + 116 + nA) = vA;
        *reinterpret_cast<f16x4*>(c2[nxt] + r * LD2 + nA)       = vA;
        *reinterpret_cast<f16x4*>(c1[nxt] + r * LD1 + 116 + nB) = vB;
        *reinterpret_cast<f16x4*>(c2[nxt] + r * LD2 + nB)       = vB;
      }
    } else if (w == 6) {
      if (p >= 1 && p < SEQT + 1) {  // L1 tile 4
        f16x8 B[6]; loadB<6>(B, c1[cur], LD1, r, kb);
        f32x4 a4[3];
        const int n4 = 64 + 4 * g;
        init3(a4, b1s, 80, n4);
        mma_tile<0, 6>(a4, wW, B);
        const f16x4 v4 = combine3(a4);
        if (n4 < 76) {
          *reinterpret_cast<f16x4*>(c1[nxt] + r * LD1 + 116 + n4) = v4;
          *reinterpret_cast<f16x4*>(c2[nxt] + r * LD2 + n4)       = v4;
        }
      }
      if (p >= 2 && p < SEQT + 2) {  // L2 tile 0
        f16x8 B[5]; loadB<5>(B, c2[cur], LD2, r, kb);
        f32x4 a0[3];
        const int nn = 4 * g;
        init3(a0, b2s, 64, nn);
        mma_tile<18, 5>(a0, wW, B);
        const f16x4 v0 = combine3(a0);
        *reinterpret_cast<f16x4*>(c2[nxt] + r * LD2 + 76 + nn) = v0;
      }
    } else {
      if (p >= 2 && p < SEQT + 2) {  // L2 tiles 1,2 (regs) + 3 (LDS frags)
        f16x8 B[5]; loadB<5>(B, c2[cur], LD2, r, kb);
        f32x4 a1[3], a2[3], a3[3];
        const int n1 = 16 + 4 * g, n2 = 32 + 4 * g, n3 = 48 + 4 * g;
        init3(a1, b2s, 64, n1);
        init3(a2, b2s, 64, n2);
        init3(a3, b2s, 64, n3);
        mma_tile<0, 5>(a1, wW, B);
        mma_tile<15, 5>(a2, wW, B);
        #pragma unroll
        for (int kt = 0; kt < 5; ++kt) {
          #pragma unroll
          for (int m = 0; m < 3; ++m) {
            const f16x8 a = *reinterpret_cast<const f16x8*>(wt3 + (size_t)((m * 5 + kt) * 64 + lane) * 8);
            a3[m] = mfma16(a, B[kt], a3[m]);
          }
        }
        const f16x4 v1 = combine3(a1);
        const f16x4 v2 = combine3(a2);
        const f16x4 v3 = combine3(a3);
        *reinterpret_cast<f16x4*>(c2[nxt] + r * LD2 + 76 + n1) = v1;
        *reinterpret_cast<f16x4*>(c2[nxt] + r * LD2 + 76 + n2) = v2;
        *reinterpret_cast<f16x4*>(c2[nxt] + r * LD2 + 76 + n3) = v3;
      }
    }

    // stage x(p+1) into c0[nxt][:, 0:64)
    if (p < SEQT - 1) {
      const int rr = tid >> 6, cc = tid & 63;
      c0[nxt][rr * LD0 + cc]       = (_Float16)xr0;
      c0[nxt][(8 + rr) * LD0 + cc] = (_Float16)xr1;
    }
    __syncthreads();
  }
}

extern "C" void kernel_launch(void* const* d_in, const int* in_sizes, int n_in,
                              void* d_out, int out_size, void* d_ws, size_t ws_size,
                              hipStream_t stream) {
  KArgs args;
  for (int i = 0; i < 30; ++i) args.in[i] = (const float*)d_in[i];
  args.out = (float*)d_out;
  ncp_fused<<<dim3(32), dim3(NTH), 0, stream>>>(args);
}